// Round 7
// baseline (937.279 us; speedup 1.0000x reference)
//
#include <hip/hip_runtime.h>

#define NN 170000
#define NE 1200000
#define F_IN 128
#define F_HID 256
#define F_OUT 40
#define BN_EPS 1e-5f
#define SCAN_B ((NN + 255) / 256)

typedef __attribute__((ext_vector_type(8))) short short8;
typedef __attribute__((ext_vector_type(4))) float f32x4;
typedef __attribute__((ext_vector_type(4))) unsigned short us4;
typedef __attribute__((ext_vector_type(4))) unsigned int u32x4;

// ---------------- bf16 helpers (manual, RNE) ----------------
__device__ __forceinline__ float b2f(unsigned short u) {
    union { unsigned x; float f; } c; c.x = ((unsigned)u) << 16; return c.f;
}
__device__ __forceinline__ unsigned short f2b(float f) {
    union { float f; unsigned x; } c; c.f = f;
    unsigned r = (c.x + 0x7FFFu + ((c.x >> 16) & 1u)) >> 16;
    return (unsigned short)r;
}
// BN+ReLU two packed bf16 lanes of one uint
__device__ __forceinline__ unsigned bn2(unsigned u, float a0, float b0, float a1, float b1) {
    float lo = b2f((unsigned short)(u & 0xffffu));
    float hi = b2f((unsigned short)(u >> 16));
    lo = fmaxf(lo * a0 + b0, 0.0f);
    hi = fmaxf(hi * a1 + b1, 0.0f);
    return (unsigned)f2b(lo) | ((unsigned)f2b(hi) << 16);
}

// ---------------- CSR construction ----------------
__global__ void count_kernel(const int* __restrict__ src, const int* __restrict__ dst,
                             int* __restrict__ cnt_src, int* __restrict__ cnt_dst, int E) {
    int e = blockIdx.x * blockDim.x + threadIdx.x;
    if (e < E) {
        atomicAdd(&cnt_src[src[e]], 1);
        atomicAdd(&cnt_dst[dst[e]], 1);
    }
}

__global__ void norm_kernel(const int* __restrict__ cnt_src, const int* __restrict__ cnt_dst,
                            float* __restrict__ norm_src, float* __restrict__ norm_dst, int N) {
    int i = blockIdx.x * blockDim.x + threadIdx.x;
    if (i < N) {
        norm_src[i] = rsqrtf((float)max(cnt_src[i], 1));
        norm_dst[i] = rsqrtf((float)max(cnt_dst[i], 1));
    }
}

__global__ void scan_block_kernel(const int* __restrict__ cnt, int* __restrict__ local,
                                  int* __restrict__ partials, int N) {
    __shared__ int s[256];
    int t = threadIdx.x;
    int idx = blockIdx.x * 256 + t;
    int v = (idx < N) ? cnt[idx] : 0;
    s[t] = v;
    __syncthreads();
    #pragma unroll
    for (int off = 1; off < 256; off <<= 1) {
        int x = (t >= off) ? s[t - off] : 0;
        __syncthreads();
        s[t] += x;
        __syncthreads();
    }
    if (idx < N) local[idx] = s[t] - v;
    if (t == 255) partials[blockIdx.x] = s[t];
}

__global__ void scan_partials_kernel(int* __restrict__ partials, int B) {
    __shared__ int s[1024];
    int t = threadIdx.x;
    int v = (t < B) ? partials[t] : 0;
    s[t] = v;
    __syncthreads();
    #pragma unroll
    for (int off = 1; off < 1024; off <<= 1) {
        int x = (t >= off) ? s[t - off] : 0;
        __syncthreads();
        s[t] += x;
        __syncthreads();
    }
    if (t < B) partials[t] = s[t] - v;
}

__global__ void scan_add_kernel(const int* __restrict__ local, const int* __restrict__ partials,
                                int* __restrict__ row_ptr, int N) {
    int idx = blockIdx.x * blockDim.x + threadIdx.x;
    if (idx < N) row_ptr[idx] = local[idx] + partials[idx >> 8];
    if (idx == 0) row_ptr[N] = NE;
}

__global__ void fill_kernel(const int* __restrict__ src, const int* __restrict__ dst,
                            const int* __restrict__ row_ptr, int* __restrict__ fill,
                            int* __restrict__ csr_src, int E) {
    int e = blockIdx.x * blockDim.x + threadIdx.x;
    if (e < E) {
        int d = dst[e];
        int pos = row_ptr[d] + atomicAdd(&fill[d], 1);
        csr_src[pos] = src[e];
    }
}

// ---------------- feat f32 -> bf16, pre-scaled by norm_src[row] ----------------
__global__ void cast_feat_kernel(const float* __restrict__ feat, const float* __restrict__ norm_src,
                                 unsigned short* __restrict__ featb) {
    unsigned idx = blockIdx.x * blockDim.x + threadIdx.x;
    if (idx >= (unsigned)NN * (F_IN / 4)) return;
    float ns = norm_src[idx / (F_IN / 4)];
    f32x4 v = __builtin_nontemporal_load((const f32x4*)(feat + (size_t)idx * 4));
    us4 o; o.x = f2b(v.x * ns); o.y = f2b(v.y * ns); o.z = f2b(v.z * ns); o.w = f2b(v.w * ns);
    *(us4*)(featb + (size_t)idx * 4) = o;
}

// ---------------- apply0: h0' = bf16(relu(h0_pre*a+b) * norm_src[row]), 8 els/thread ----------
__global__ void apply_bn_scale_kernel(const unsigned short* __restrict__ in,
                                      const float* __restrict__ bna, const float* __restrict__ bnb,
                                      const float* __restrict__ norm_src,
                                      unsigned short* __restrict__ outp) {
    unsigned idx = blockIdx.x * blockDim.x + threadIdx.x;   // N*32 threads, 8 els each
    if (idx >= (unsigned)NN * (F_HID / 8)) return;
    unsigned row = idx / (F_HID / 8);
    unsigned c8 = (idx % (F_HID / 8)) * 8;
    float ns = norm_src[row];
    u32x4 u = *(const u32x4*)(in + (size_t)idx * 8);
    const f32x4 a0 = *(const f32x4*)(bna + c8);
    const f32x4 a1 = *(const f32x4*)(bna + c8 + 4);
    const f32x4 s0 = *(const f32x4*)(bnb + c8);
    const f32x4 s1 = *(const f32x4*)(bnb + c8 + 4);
    u.x = bn2(u.x, a0.x * ns, s0.x * ns, a0.y * ns, s0.y * ns);
    u.y = bn2(u.y, a0.z * ns, s0.z * ns, a0.w * ns, s0.w * ns);
    u.z = bn2(u.z, a1.x * ns, s1.x * ns, a1.y * ns, s1.y * ns);
    u.w = bn2(u.w, a1.z * ns, s1.z * ns, a1.w * ns, s1.w * ns);
    __builtin_nontemporal_store(u, (u32x4*)(outp + (size_t)idx * 8));
}

// ---------------- pure-sum gather, bf16 in/out, template width ----------------
template<int F>
__global__ void gather_sum_kernel(const unsigned short* __restrict__ h, const int* __restrict__ row_ptr,
                                  const int* __restrict__ csr_src,
                                  unsigned short* __restrict__ out, int N) {
    constexpr int TPN = F / 4;
    unsigned idx = blockIdx.x * blockDim.x + threadIdx.x;
    if (idx >= (unsigned)N * TPN) return;
    unsigned node = idx / TPN;
    unsigned g = idx % TPN;
    int beg = row_ptr[node], end = row_ptr[node + 1];
    float ax0 = 0.f, ay0 = 0.f, az0 = 0.f, aw0 = 0.f;
    float ax1 = 0.f, ay1 = 0.f, az1 = 0.f, aw1 = 0.f;
    int e = beg;
    for (; e + 2 <= end; e += 2) {
        int s0 = csr_src[e], s1 = csr_src[e + 1];
        const us4 v0 = *(const us4*)(h + (size_t)s0 * F + g * 4);
        const us4 v1 = *(const us4*)(h + (size_t)s1 * F + g * 4);
        ax0 += b2f(v0.x); ay0 += b2f(v0.y); az0 += b2f(v0.z); aw0 += b2f(v0.w);
        ax1 += b2f(v1.x); ay1 += b2f(v1.y); az1 += b2f(v1.z); aw1 += b2f(v1.w);
    }
    if (e < end) {
        int s0 = csr_src[e];
        const us4 v0 = *(const us4*)(h + (size_t)s0 * F + g * 4);
        ax0 += b2f(v0.x); ay0 += b2f(v0.y); az0 += b2f(v0.z); aw0 += b2f(v0.w);
    }
    us4 o;
    o.x = f2b(ax0 + ax1); o.y = f2b(ay0 + ay1); o.z = f2b(az0 + az1); o.w = f2b(aw0 + aw1);
    __builtin_nontemporal_store(o, (us4*)(out + (size_t)node * F + g * 4));
}

// ---------------- final gather: f32 in (width 40, pre-scaled by norm_src) + nd + bias ----------
__global__ void gather_final_kernel(const float* __restrict__ h, const int* __restrict__ row_ptr,
                                    const int* __restrict__ csr_src,
                                    const float* __restrict__ norm_dst, const float* __restrict__ bias,
                                    float* __restrict__ out, int N) {
    constexpr int TPN = F_OUT / 4;
    unsigned idx = blockIdx.x * blockDim.x + threadIdx.x;
    if (idx >= (unsigned)N * TPN) return;
    unsigned node = idx / TPN;
    unsigned g = idx % TPN;
    int beg = row_ptr[node], end = row_ptr[node + 1];
    float ax0 = 0.f, ay0 = 0.f, az0 = 0.f, aw0 = 0.f;
    float ax1 = 0.f, ay1 = 0.f, az1 = 0.f, aw1 = 0.f;
    int e = beg;
    for (; e + 2 <= end; e += 2) {
        int s0 = csr_src[e], s1 = csr_src[e + 1];
        const f32x4 v0 = *(const f32x4*)(h + (size_t)s0 * F_OUT + g * 4);
        const f32x4 v1 = *(const f32x4*)(h + (size_t)s1 * F_OUT + g * 4);
        ax0 += v0.x; ay0 += v0.y; az0 += v0.z; aw0 += v0.w;
        ax1 += v1.x; ay1 += v1.y; az1 += v1.z; aw1 += v1.w;
    }
    if (e < end) {
        int s0 = csr_src[e];
        const f32x4 v0 = *(const f32x4*)(h + (size_t)s0 * F_OUT + g * 4);
        ax0 += v0.x; ay0 += v0.y; az0 += v0.z; aw0 += v0.w;
    }
    float nd = norm_dst[node];
    const f32x4 b = *(const f32x4*)(bias + g * 4);
    f32x4 r;
    r.x = (ax0 + ax1) * nd + b.x; r.y = (ay0 + ay1) * nd + b.y;
    r.z = (az0 + az1) * nd + b.z; r.w = (aw0 + aw1) * nd + b.w;
    __builtin_nontemporal_store(r, (f32x4*)(out + (size_t)node * F_OUT + g * 4));
}

// ---------------- weight transpose+cast: W[K][M] f32 -> Wt[MP][K] bf16 (zero-pad m>=M) ----
template<int K, int M, int MP>
__global__ void wt_kernel(const float* __restrict__ W, unsigned short* __restrict__ Wt) {
    int idx = blockIdx.x * blockDim.x + threadIdx.x;
    if (idx >= MP * K) return;
    int m = idx / K, k = idx % K;
    float v = (m < M) ? W[(size_t)k * M + m] : 0.0f;
    Wt[idx] = f2b(v);
}

// ---------------- BN finalize: col sums -> per-col scale a, shift b ----------------
__global__ void bn_finalize_kernel(const float* __restrict__ sum, const float* __restrict__ sumsq,
                                   const float* __restrict__ gamma, const float* __restrict__ beta,
                                   float* __restrict__ a, float* __restrict__ b) {
    int c = threadIdx.x;
    float invN = 1.0f / (float)NN;
    float mean = sum[c] * invN;
    float var = sumsq[c] * invN - mean * mean;
    float inv = rsqrtf(var + BN_EPS);
    float ac = inv * gamma[c];
    a[c] = ac;
    b[c] = beta[c] - mean * ac;
}

// ---------------- MFMA bf16 GEMM ----------------
template<int K, int BN_T, int WM_T, int WN_T, int WAVES_N, bool SCALE, bool BF16OUT, int M_OUT,
         bool STATS, bool APPLYBN>
__global__ __launch_bounds__(256) void mfma_gemm(const unsigned short* __restrict__ A,
                                                 const unsigned short* __restrict__ Wt,
                                                 const float* __restrict__ rowscale,
                                                 void* __restrict__ C,
                                                 const float* __restrict__ bna,
                                                 const float* __restrict__ bnb,
                                                 float* __restrict__ osum,
                                                 float* __restrict__ osumsq, int N) {
    constexpr int BM = 128, BK = 64, AP = 72;  // +8 bf16 pad: 144 B stride, 2-way banks (free)
    __shared__ unsigned short As[BM * AP];
    __shared__ unsigned short Bs[BN_T * AP];

    const int lane = threadIdx.x & 63;
    const int wave = threadIdx.x >> 6;
    const int wr = wave / WAVES_N, wc = wave % WAVES_N;
    const int quad = lane >> 4, l15 = lane & 15;
    const int r0 = blockIdx.y * BM;
    const int c0 = blockIdx.x * BN_T;
    const int wmb = wr * WM_T * 16;
    const int wnb = wc * WN_T * 16;

    f32x4 acc[WM_T][WN_T] = {};

    for (int k0 = 0; k0 < K; k0 += BK) {
        #pragma unroll
        for (int p = 0; p < BM * (BK / 8) / 256; p++) {
            int c = threadIdx.x + p * 256;
            int row = c >> 3, off = (c & 7) * 8;
            int gr = r0 + row;
            u32x4 v = {0u, 0u, 0u, 0u};
            if (gr < N) {
                v = *(const u32x4*)(A + (size_t)gr * K + k0 + off);
                if (APPLYBN) {
                    int kb = k0 + off;
                    const f32x4 a0 = *(const f32x4*)(bna + kb);
                    const f32x4 a1 = *(const f32x4*)(bna + kb + 4);
                    const f32x4 s0 = *(const f32x4*)(bnb + kb);
                    const f32x4 s1 = *(const f32x4*)(bnb + kb + 4);
                    v.x = bn2(v.x, a0.x, s0.x, a0.y, s0.y);
                    v.y = bn2(v.y, a0.z, s0.z, a0.w, s0.w);
                    v.z = bn2(v.z, a1.x, s1.x, a1.y, s1.y);
                    v.w = bn2(v.w, a1.z, s1.z, a1.w, s1.w);
                }
            }
            *(u32x4*)(As + row * AP + off) = v;
        }
        #pragma unroll
        for (int p = 0; p < BN_T * (BK / 8) / 256; p++) {
            int c = threadIdx.x + p * 256;
            int m = c >> 3, off = (c & 7) * 8;
            *(u32x4*)(Bs + m * AP + off) = *(const u32x4*)(Wt + (size_t)(c0 + m) * K + k0 + off);
        }
        __syncthreads();
        #pragma unroll
        for (int kk = 0; kk < BK; kk += 32) {
            short8 af[WM_T], bf[WN_T];
            #pragma unroll
            for (int i = 0; i < WM_T; i++)
                af[i] = *(const short8*)(As + (wmb + i * 16 + l15) * AP + kk + quad * 8);
            #pragma unroll
            for (int j = 0; j < WN_T; j++)
                bf[j] = *(const short8*)(Bs + (wnb + j * 16 + l15) * AP + kk + quad * 8);
            #pragma unroll
            for (int i = 0; i < WM_T; i++)
                #pragma unroll
                for (int j = 0; j < WN_T; j++)
                    acc[i][j] = __builtin_amdgcn_mfma_f32_16x16x32_bf16(af[i], bf[j], acc[i][j], 0, 0, 0);
        }
        __syncthreads();
    }

    // epilogue: C/D layout col=lane&15, row=quad*4+reg
    float s[WN_T] = {}, ss[WN_T] = {};
    #pragma unroll
    for (int i = 0; i < WM_T; i++) {
        #pragma unroll
        for (int r = 0; r < 4; r++) {
            int row = r0 + wmb + i * 16 + quad * 4 + r;
            if (row >= N) continue;
            float scale = SCALE ? rowscale[row] : 1.0f;
            #pragma unroll
            for (int j = 0; j < WN_T; j++) {
                float v = acc[i][j][r] * scale;
                if (STATS) { s[j] += v; ss[j] += v * v; }
                int col = c0 + wnb + j * 16 + l15;
                if (col < M_OUT) {
                    if (BF16OUT) ((unsigned short*)C)[(size_t)row * M_OUT + col] = f2b(v);
                    else         ((float*)C)[(size_t)row * M_OUT + col] = v;
                }
            }
        }
    }
    if (STATS) {
        #pragma unroll
        for (int j = 0; j < WN_T; j++) {
            float t = s[j], t2 = ss[j];
            t  += __shfl_xor(t, 16);  t  += __shfl_xor(t, 32);
            t2 += __shfl_xor(t2, 16); t2 += __shfl_xor(t2, 32);
            if (quad == 0) {
                int col = c0 + wnb + j * 16 + l15;
                atomicAdd(&osum[col], t);
                atomicAdd(&osumsq[col], t2);
            }
        }
    }
}

extern "C" void kernel_launch(void* const* d_in, const int* in_sizes, int n_in,
                              void* d_out, int out_size, void* d_ws, size_t ws_size,
                              hipStream_t stream) {
    const float* feat  = (const float*)d_in[0];
    const int*   src   = (const int*)d_in[1];
    const int*   dst   = (const int*)d_in[2];
    const float* W0    = (const float*)d_in[3];
    const float* W1    = (const float*)d_in[4];
    const float* W2    = (const float*)d_in[5];
    const float* b2    = (const float*)d_in[6];
    const float* g0    = (const float*)d_in[7];
    const float* beta0 = (const float*)d_in[8];
    const float* g1    = (const float*)d_in[9];
    const float* beta1 = (const float*)d_in[10];
    float* out = (float*)d_out;

    const int N = NN, E = NE;

    // ---- workspace carve (~225 MB; proven budget >= 268 MB)
    char* ws = (char*)d_ws;
    auto alloc_b = [&](size_t bytes) {
        void* p = (void*)ws;
        ws += ((bytes + 255) / 256) * 256;
        return p;
    };
    float* norm_src = (float*)alloc_b((size_t)N * 4);
    float* norm_dst = (float*)alloc_b((size_t)N * 4);
    int*   row_ptr  = (int*)alloc_b((size_t)(N + 1) * 4);
    int*   csr_src  = (int*)alloc_b((size_t)E * 4);
    float* bnsum    = (float*)alloc_b(512 * 4);
    float* bn_a0    = (float*)alloc_b(256 * 4);
    float* bn_b0    = (float*)alloc_b(256 * 4);
    float* bn_a1    = (float*)alloc_b(256 * 4);
    float* bn_b1    = (float*)alloc_b(256 * 4);
    unsigned short* Wt0 = (unsigned short*)alloc_b((size_t)256 * 128 * 2);
    unsigned short* Wt1 = (unsigned short*)alloc_b((size_t)256 * 256 * 2);
    unsigned short* Wt2 = (unsigned short*)alloc_b((size_t)64 * 256 * 2);
    void* B1 = alloc_b((size_t)N * 512);   // N x 256 bf16 OR N x 40 f32
    void* B2 = alloc_b((size_t)N * 512);
    unsigned short* featb = (unsigned short*)alloc_b((size_t)N * F_IN * 2);
    float* bnsumsq = bnsum + 256;

    unsigned short* B1b = (unsigned short*)B1;
    unsigned short* B2b = (unsigned short*)B2;
    float*          B2f = (float*)B2;

    // CSR-build scratch aliased at head of B1 (dead before gather0 writes B1)
    int* cnt_src  = (int*)B1;
    int* cnt_dst  = cnt_src + N;
    int* fill     = cnt_dst + N;
    int* local    = fill + N;
    int* partials = local + N;

    // ---- CSR build + norms + weight prep + feat cast (pre-scaled by norm_src)
    hipMemsetAsync(cnt_src, 0, ((size_t)4 * N + 1024) * 4, stream);
    count_kernel<<<(E + 255) / 256, 256, 0, stream>>>(src, dst, cnt_src, cnt_dst, E);
    norm_kernel<<<(N + 255) / 256, 256, 0, stream>>>(cnt_src, cnt_dst, norm_src, norm_dst, N);
    scan_block_kernel<<<SCAN_B, 256, 0, stream>>>(cnt_dst, local, partials, N);
    scan_partials_kernel<<<1, 1024, 0, stream>>>(partials, SCAN_B);
    scan_add_kernel<<<(N + 255) / 256, 256, 0, stream>>>(local, partials, row_ptr, N);
    fill_kernel<<<(E + 255) / 256, 256, 0, stream>>>(src, dst, row_ptr, fill, csr_src, E);
    wt_kernel<128, 256, 256><<<(256 * 128 + 255) / 256, 256, 0, stream>>>(W0, Wt0);
    wt_kernel<256, 256, 256><<<(256 * 256 + 255) / 256, 256, 0, stream>>>(W1, Wt1);
    wt_kernel<256, 40, 64><<<(64 * 256 + 255) / 256, 256, 0, stream>>>(W2, Wt2);
    cast_feat_kernel<<<((unsigned)N * (F_IN / 4) + 255) / 256, 256, 0, stream>>>(feat, norm_src, featb);

    const int GB = (N + 127) / 128;

    // ---- layer 0: gather0 (pure sum) -> B1, GEMM0 (xnorm_dst, stats, 256-wide block) -> B2
    {
        unsigned total = (unsigned)N * (F_IN / 4);
        gather_sum_kernel<F_IN><<<(total + 255) / 256, 256, 0, stream>>>(featb, row_ptr, csr_src, B1b, N);
    }
    hipMemsetAsync(bnsum, 0, 512 * 4, stream);
    mfma_gemm<128, 256, 4, 8, 2, true, true, 256, true, false><<<dim3(1, GB), 256, 0, stream>>>(
        B1b, Wt0, norm_dst, B2, nullptr, nullptr, bnsum, bnsumsq, N);
    bn_finalize_kernel<<<1, 256, 0, stream>>>(bnsum, bnsumsq, g0, beta0, bn_a0, bn_b0);

    // ---- layer 1: apply0 (BN+ReLU+norm_src) B2 -> B1, gather1 (pure sum) B1 -> B2,
    //               GEMM1 (xnorm_dst, stats) B2 -> B1
    apply_bn_scale_kernel<<<((unsigned)N * (F_HID / 8) + 255) / 256, 256, 0, stream>>>(
        B2b, bn_a0, bn_b0, norm_src, B1b);
    {
        unsigned total = (unsigned)N * (F_HID / 4);
        gather_sum_kernel<F_HID><<<(total + 255) / 256, 256, 0, stream>>>(B1b, row_ptr, csr_src, B2b, N);
    }
    hipMemsetAsync(bnsum, 0, 512 * 4, stream);
    mfma_gemm<256, 256, 4, 8, 2, true, true, 256, true, false><<<dim3(1, GB), 256, 0, stream>>>(
        B2b, Wt1, norm_dst, B1, nullptr, nullptr, bnsum, bnsumsq, N);
    bn_finalize_kernel<<<1, 256, 0, stream>>>(bnsum, bnsumsq, g1, beta1, bn_a1, bn_b1);

    // ---- layer 2: GEMM2 (BN+ReLU in staging, epilogue x norm_src) B1 -> B2f (N x 40 f32),
    //               final gather (pure sum, x norm_dst + b2) -> out
    mfma_gemm<256, 64, 2, 4, 1, true, false, 40, false, true><<<dim3(1, GB), 256, 0, stream>>>(
        B1b, Wt2, norm_src, B2, bn_a1, bn_b1, nullptr, nullptr, N);
    {
        unsigned total = (unsigned)N * (F_OUT / 4);
        gather_final_kernel<<<(total + 255) / 256, 256, 0, stream>>>(
            B2f, row_ptr, csr_src, norm_dst, b2, out, N);
    }
}

// Round 8
// 849.996 us; speedup vs baseline: 1.1027x; 1.1027x over previous
//
#include <hip/hip_runtime.h>

#define NN 170000
#define NE 1200000
#define F_IN 128
#define F_HID 256
#define F_OUT 40
#define BN_EPS 1e-5f
#define SCAN_B ((NN + 255) / 256)

typedef __attribute__((ext_vector_type(8))) short short8;
typedef __attribute__((ext_vector_type(4))) float f32x4;
typedef __attribute__((ext_vector_type(4))) unsigned short us4;
typedef __attribute__((ext_vector_type(4))) unsigned int u32x4;

// ---------------- bf16 helpers (manual, RNE) ----------------
__device__ __forceinline__ float b2f(unsigned short u) {
    union { unsigned x; float f; } c; c.x = ((unsigned)u) << 16; return c.f;
}
__device__ __forceinline__ unsigned short f2b(float f) {
    union { float f; unsigned x; } c; c.f = f;
    unsigned r = (c.x + 0x7FFFu + ((c.x >> 16) & 1u)) >> 16;
    return (unsigned short)r;
}
// BN+ReLU two packed bf16 lanes of one uint
__device__ __forceinline__ unsigned bn2(unsigned u, float a0, float b0, float a1, float b1) {
    float lo = b2f((unsigned short)(u & 0xffffu));
    float hi = b2f((unsigned short)(u >> 16));
    lo = fmaxf(lo * a0 + b0, 0.0f);
    hi = fmaxf(hi * a1 + b1, 0.0f);
    return (unsigned)f2b(lo) | ((unsigned)f2b(hi) << 16);
}

// ---------------- CSR construction ----------------
__global__ void count_kernel(const int* __restrict__ src, const int* __restrict__ dst,
                             int* __restrict__ cnt_src, int* __restrict__ cnt_dst, int E) {
    int e = blockIdx.x * blockDim.x + threadIdx.x;
    if (e < E) {
        atomicAdd(&cnt_src[src[e]], 1);
        atomicAdd(&cnt_dst[dst[e]], 1);
    }
}

__global__ void norm_kernel(const int* __restrict__ cnt_src, const int* __restrict__ cnt_dst,
                            float* __restrict__ norm_src, float* __restrict__ norm_dst, int N) {
    int i = blockIdx.x * blockDim.x + threadIdx.x;
    if (i < N) {
        norm_src[i] = rsqrtf((float)max(cnt_src[i], 1));
        norm_dst[i] = rsqrtf((float)max(cnt_dst[i], 1));
    }
}

__global__ void scan_block_kernel(const int* __restrict__ cnt, int* __restrict__ local,
                                  int* __restrict__ partials, int N) {
    __shared__ int s[256];
    int t = threadIdx.x;
    int idx = blockIdx.x * 256 + t;
    int v = (idx < N) ? cnt[idx] : 0;
    s[t] = v;
    __syncthreads();
    #pragma unroll
    for (int off = 1; off < 256; off <<= 1) {
        int x = (t >= off) ? s[t - off] : 0;
        __syncthreads();
        s[t] += x;
        __syncthreads();
    }
    if (idx < N) local[idx] = s[t] - v;
    if (t == 255) partials[blockIdx.x] = s[t];
}

__global__ void scan_partials_kernel(int* __restrict__ partials, int B) {
    __shared__ int s[1024];
    int t = threadIdx.x;
    int v = (t < B) ? partials[t] : 0;
    s[t] = v;
    __syncthreads();
    #pragma unroll
    for (int off = 1; off < 1024; off <<= 1) {
        int x = (t >= off) ? s[t - off] : 0;
        __syncthreads();
        s[t] += x;
        __syncthreads();
    }
    if (t < B) partials[t] = s[t] - v;
}

__global__ void scan_add_kernel(const int* __restrict__ local, const int* __restrict__ partials,
                                int* __restrict__ row_ptr, int N) {
    int idx = blockIdx.x * blockDim.x + threadIdx.x;
    if (idx < N) row_ptr[idx] = local[idx] + partials[idx >> 8];
    if (idx == 0) row_ptr[N] = NE;
}

__global__ void fill_kernel(const int* __restrict__ src, const int* __restrict__ dst,
                            const int* __restrict__ row_ptr, int* __restrict__ fill,
                            int* __restrict__ csr_src, int E) {
    int e = blockIdx.x * blockDim.x + threadIdx.x;
    if (e < E) {
        int d = dst[e];
        int pos = row_ptr[d] + atomicAdd(&fill[d], 1);
        csr_src[pos] = src[e];
    }
}

// ---------------- feat f32 -> bf16, pre-scaled by norm_src[row] ----------------
__global__ void cast_feat_kernel(const float* __restrict__ feat, const float* __restrict__ norm_src,
                                 unsigned short* __restrict__ featb) {
    unsigned idx = blockIdx.x * blockDim.x + threadIdx.x;
    if (idx >= (unsigned)NN * (F_IN / 4)) return;
    float ns = norm_src[idx / (F_IN / 4)];
    f32x4 v = __builtin_nontemporal_load((const f32x4*)(feat + (size_t)idx * 4));
    us4 o; o.x = f2b(v.x * ns); o.y = f2b(v.y * ns); o.z = f2b(v.z * ns); o.w = f2b(v.w * ns);
    *(us4*)(featb + (size_t)idx * 4) = o;
}

// ---------------- apply0: h0' = bf16(relu(h0_pre*a+b) * norm_src[row]), 8 els/thread ----------
__global__ void apply_bn_scale_kernel(const unsigned short* __restrict__ in,
                                      const float* __restrict__ bna, const float* __restrict__ bnb,
                                      const float* __restrict__ norm_src,
                                      unsigned short* __restrict__ outp) {
    unsigned idx = blockIdx.x * blockDim.x + threadIdx.x;   // N*32 threads, 8 els each
    if (idx >= (unsigned)NN * (F_HID / 8)) return;
    unsigned row = idx / (F_HID / 8);
    unsigned c8 = (idx % (F_HID / 8)) * 8;
    float ns = norm_src[row];
    u32x4 u = *(const u32x4*)(in + (size_t)idx * 8);
    const f32x4 a0 = *(const f32x4*)(bna + c8);
    const f32x4 a1 = *(const f32x4*)(bna + c8 + 4);
    const f32x4 s0 = *(const f32x4*)(bnb + c8);
    const f32x4 s1 = *(const f32x4*)(bnb + c8 + 4);
    u.x = bn2(u.x, a0.x * ns, s0.x * ns, a0.y * ns, s0.y * ns);
    u.y = bn2(u.y, a0.z * ns, s0.z * ns, a0.w * ns, s0.w * ns);
    u.z = bn2(u.z, a1.x * ns, s1.x * ns, a1.y * ns, s1.y * ns);
    u.w = bn2(u.w, a1.z * ns, s1.z * ns, a1.w * ns, s1.w * ns);
    __builtin_nontemporal_store(u, (u32x4*)(outp + (size_t)idx * 8));
}

// ---------------- pure-sum gather, bf16 in/out, template width ----------------
template<int F>
__global__ void gather_sum_kernel(const unsigned short* __restrict__ h, const int* __restrict__ row_ptr,
                                  const int* __restrict__ csr_src,
                                  unsigned short* __restrict__ out, int N) {
    constexpr int TPN = F / 4;
    unsigned idx = blockIdx.x * blockDim.x + threadIdx.x;
    if (idx >= (unsigned)N * TPN) return;
    unsigned node = idx / TPN;
    unsigned g = idx % TPN;
    int beg = row_ptr[node], end = row_ptr[node + 1];
    float ax0 = 0.f, ay0 = 0.f, az0 = 0.f, aw0 = 0.f;
    float ax1 = 0.f, ay1 = 0.f, az1 = 0.f, aw1 = 0.f;
    int e = beg;
    for (; e + 2 <= end; e += 2) {
        int s0 = csr_src[e], s1 = csr_src[e + 1];
        const us4 v0 = *(const us4*)(h + (size_t)s0 * F + g * 4);
        const us4 v1 = *(const us4*)(h + (size_t)s1 * F + g * 4);
        ax0 += b2f(v0.x); ay0 += b2f(v0.y); az0 += b2f(v0.z); aw0 += b2f(v0.w);
        ax1 += b2f(v1.x); ay1 += b2f(v1.y); az1 += b2f(v1.z); aw1 += b2f(v1.w);
    }
    if (e < end) {
        int s0 = csr_src[e];
        const us4 v0 = *(const us4*)(h + (size_t)s0 * F + g * 4);
        ax0 += b2f(v0.x); ay0 += b2f(v0.y); az0 += b2f(v0.z); aw0 += b2f(v0.w);
    }
    us4 o;
    o.x = f2b(ax0 + ax1); o.y = f2b(ay0 + ay1); o.z = f2b(az0 + az1); o.w = f2b(aw0 + aw1);
    __builtin_nontemporal_store(o, (us4*)(out + (size_t)node * F + g * 4));
}

// ---------------- final gather: f32 in (width 40, pre-scaled by norm_src) + nd + bias ----------
__global__ void gather_final_kernel(const float* __restrict__ h, const int* __restrict__ row_ptr,
                                    const int* __restrict__ csr_src,
                                    const float* __restrict__ norm_dst, const float* __restrict__ bias,
                                    float* __restrict__ out, int N) {
    constexpr int TPN = F_OUT / 4;
    unsigned idx = blockIdx.x * blockDim.x + threadIdx.x;
    if (idx >= (unsigned)N * TPN) return;
    unsigned node = idx / TPN;
    unsigned g = idx % TPN;
    int beg = row_ptr[node], end = row_ptr[node + 1];
    float ax0 = 0.f, ay0 = 0.f, az0 = 0.f, aw0 = 0.f;
    float ax1 = 0.f, ay1 = 0.f, az1 = 0.f, aw1 = 0.f;
    int e = beg;
    for (; e + 2 <= end; e += 2) {
        int s0 = csr_src[e], s1 = csr_src[e + 1];
        const f32x4 v0 = *(const f32x4*)(h + (size_t)s0 * F_OUT + g * 4);
        const f32x4 v1 = *(const f32x4*)(h + (size_t)s1 * F_OUT + g * 4);
        ax0 += v0.x; ay0 += v0.y; az0 += v0.z; aw0 += v0.w;
        ax1 += v1.x; ay1 += v1.y; az1 += v1.z; aw1 += v1.w;
    }
    if (e < end) {
        int s0 = csr_src[e];
        const f32x4 v0 = *(const f32x4*)(h + (size_t)s0 * F_OUT + g * 4);
        ax0 += v0.x; ay0 += v0.y; az0 += v0.z; aw0 += v0.w;
    }
    float nd = norm_dst[node];
    const f32x4 b = *(const f32x4*)(bias + g * 4);
    f32x4 r;
    r.x = (ax0 + ax1) * nd + b.x; r.y = (ay0 + ay1) * nd + b.y;
    r.z = (az0 + az1) * nd + b.z; r.w = (aw0 + aw1) * nd + b.w;
    __builtin_nontemporal_store(r, (f32x4*)(out + (size_t)node * F_OUT + g * 4));
}

// ---------------- weight transpose+cast: W[K][M] f32 -> Wt[MP][K] bf16 (zero-pad m>=M) ----
template<int K, int M, int MP>
__global__ void wt_kernel(const float* __restrict__ W, unsigned short* __restrict__ Wt) {
    int idx = blockIdx.x * blockDim.x + threadIdx.x;
    if (idx >= MP * K) return;
    int m = idx / K, k = idx % K;
    float v = (m < M) ? W[(size_t)k * M + m] : 0.0f;
    Wt[idx] = f2b(v);
}

// ---------------- BN finalize: col sums -> per-col scale a, shift b ----------------
__global__ void bn_finalize_kernel(const float* __restrict__ sum, const float* __restrict__ sumsq,
                                   const float* __restrict__ gamma, const float* __restrict__ beta,
                                   float* __restrict__ a, float* __restrict__ b) {
    int c = threadIdx.x;
    float invN = 1.0f / (float)NN;
    float mean = sum[c] * invN;
    float var = sumsq[c] * invN - mean * mean;
    float inv = rsqrtf(var + BN_EPS);
    float ac = inv * gamma[c];
    a[c] = ac;
    b[c] = beta[c] - mean * ac;
}

// ---------------- MFMA bf16 GEMM ----------------
// Proven config (R5): BN_T=128, WM_T=4, WN_T=4, WAVES_N=2 -> 64 acc VGPRs, 36 KB LDS,
// dim3(2, GB) grid. 256-wide block (R7) collapsed occupancy to ~1 block/CU - do not revisit.
template<int K, int BN_T, int WM_T, int WN_T, int WAVES_N, bool SCALE, bool BF16OUT, int M_OUT,
         bool STATS, bool APPLYBN>
__global__ __launch_bounds__(256) void mfma_gemm(const unsigned short* __restrict__ A,
                                                 const unsigned short* __restrict__ Wt,
                                                 const float* __restrict__ rowscale,
                                                 void* __restrict__ C,
                                                 const float* __restrict__ bna,
                                                 const float* __restrict__ bnb,
                                                 float* __restrict__ osum,
                                                 float* __restrict__ osumsq, int N) {
    constexpr int BM = 128, BK = 64, AP = 72;  // +8 bf16 pad: 144 B stride, 2-way banks (free)
    __shared__ unsigned short As[BM * AP];
    __shared__ unsigned short Bs[BN_T * AP];

    const int lane = threadIdx.x & 63;
    const int wave = threadIdx.x >> 6;
    const int wr = wave / WAVES_N, wc = wave % WAVES_N;
    const int quad = lane >> 4, l15 = lane & 15;
    const int r0 = blockIdx.y * BM;
    const int c0 = blockIdx.x * BN_T;
    const int wmb = wr * WM_T * 16;
    const int wnb = wc * WN_T * 16;

    f32x4 acc[WM_T][WN_T] = {};

    for (int k0 = 0; k0 < K; k0 += BK) {
        #pragma unroll
        for (int p = 0; p < BM * (BK / 8) / 256; p++) {
            int c = threadIdx.x + p * 256;
            int row = c >> 3, off = (c & 7) * 8;
            int gr = r0 + row;
            u32x4 v = {0u, 0u, 0u, 0u};
            if (gr < N) {
                v = *(const u32x4*)(A + (size_t)gr * K + k0 + off);
                if (APPLYBN) {
                    int kb = k0 + off;
                    const f32x4 a0 = *(const f32x4*)(bna + kb);
                    const f32x4 a1 = *(const f32x4*)(bna + kb + 4);
                    const f32x4 s0 = *(const f32x4*)(bnb + kb);
                    const f32x4 s1 = *(const f32x4*)(bnb + kb + 4);
                    v.x = bn2(v.x, a0.x, s0.x, a0.y, s0.y);
                    v.y = bn2(v.y, a0.z, s0.z, a0.w, s0.w);
                    v.z = bn2(v.z, a1.x, s1.x, a1.y, s1.y);
                    v.w = bn2(v.w, a1.z, s1.z, a1.w, s1.w);
                }
            }
            *(u32x4*)(As + row * AP + off) = v;
        }
        #pragma unroll
        for (int p = 0; p < BN_T * (BK / 8) / 256; p++) {
            int c = threadIdx.x + p * 256;
            int m = c >> 3, off = (c & 7) * 8;
            *(u32x4*)(Bs + m * AP + off) = *(const u32x4*)(Wt + (size_t)(c0 + m) * K + k0 + off);
        }
        __syncthreads();
        #pragma unroll
        for (int kk = 0; kk < BK; kk += 32) {
            short8 af[WM_T], bf[WN_T];
            #pragma unroll
            for (int i = 0; i < WM_T; i++)
                af[i] = *(const short8*)(As + (wmb + i * 16 + l15) * AP + kk + quad * 8);
            #pragma unroll
            for (int j = 0; j < WN_T; j++)
                bf[j] = *(const short8*)(Bs + (wnb + j * 16 + l15) * AP + kk + quad * 8);
            #pragma unroll
            for (int i = 0; i < WM_T; i++)
                #pragma unroll
                for (int j = 0; j < WN_T; j++)
                    acc[i][j] = __builtin_amdgcn_mfma_f32_16x16x32_bf16(af[i], bf[j], acc[i][j], 0, 0, 0);
        }
        __syncthreads();
    }

    // epilogue: C/D layout col=lane&15, row=quad*4+reg
    float s[WN_T] = {}, ss[WN_T] = {};
    #pragma unroll
    for (int i = 0; i < WM_T; i++) {
        #pragma unroll
        for (int r = 0; r < 4; r++) {
            int row = r0 + wmb + i * 16 + quad * 4 + r;
            if (row >= N) continue;
            float scale = SCALE ? rowscale[row] : 1.0f;
            #pragma unroll
            for (int j = 0; j < WN_T; j++) {
                float v = acc[i][j][r] * scale;
                if (STATS) { s[j] += v; ss[j] += v * v; }
                int col = c0 + wnb + j * 16 + l15;
                if (col < M_OUT) {
                    if (BF16OUT) ((unsigned short*)C)[(size_t)row * M_OUT + col] = f2b(v);
                    else         ((float*)C)[(size_t)row * M_OUT + col] = v;
                }
            }
        }
    }
    if (STATS) {
        #pragma unroll
        for (int j = 0; j < WN_T; j++) {
            float t = s[j], t2 = ss[j];
            t  += __shfl_xor(t, 16);  t  += __shfl_xor(t, 32);
            t2 += __shfl_xor(t2, 16); t2 += __shfl_xor(t2, 32);
            if (quad == 0) {
                int col = c0 + wnb + j * 16 + l15;
                atomicAdd(&osum[col], t);
                atomicAdd(&osumsq[col], t2);
            }
        }
    }
}

extern "C" void kernel_launch(void* const* d_in, const int* in_sizes, int n_in,
                              void* d_out, int out_size, void* d_ws, size_t ws_size,
                              hipStream_t stream) {
    const float* feat  = (const float*)d_in[0];
    const int*   src   = (const int*)d_in[1];
    const int*   dst   = (const int*)d_in[2];
    const float* W0    = (const float*)d_in[3];
    const float* W1    = (const float*)d_in[4];
    const float* W2    = (const float*)d_in[5];
    const float* b2    = (const float*)d_in[6];
    const float* g0    = (const float*)d_in[7];
    const float* beta0 = (const float*)d_in[8];
    const float* g1    = (const float*)d_in[9];
    const float* beta1 = (const float*)d_in[10];
    float* out = (float*)d_out;

    const int N = NN, E = NE;

    // ---- workspace carve (~225 MB; proven budget >= 268 MB)
    char* ws = (char*)d_ws;
    auto alloc_b = [&](size_t bytes) {
        void* p = (void*)ws;
        ws += ((bytes + 255) / 256) * 256;
        return p;
    };
    float* norm_src = (float*)alloc_b((size_t)N * 4);
    float* norm_dst = (float*)alloc_b((size_t)N * 4);
    int*   row_ptr  = (int*)alloc_b((size_t)(N + 1) * 4);
    int*   csr_src  = (int*)alloc_b((size_t)E * 4);
    float* bnsum    = (float*)alloc_b(512 * 4);
    float* bn_a0    = (float*)alloc_b(256 * 4);
    float* bn_b0    = (float*)alloc_b(256 * 4);
    float* bn_a1    = (float*)alloc_b(256 * 4);
    float* bn_b1    = (float*)alloc_b(256 * 4);
    unsigned short* Wt0 = (unsigned short*)alloc_b((size_t)256 * 128 * 2);
    unsigned short* Wt1 = (unsigned short*)alloc_b((size_t)256 * 256 * 2);
    unsigned short* Wt2 = (unsigned short*)alloc_b((size_t)64 * 256 * 2);
    void* B1 = alloc_b((size_t)N * 512);   // N x 256 bf16 OR N x 40 f32
    void* B2 = alloc_b((size_t)N * 512);
    unsigned short* featb = (unsigned short*)alloc_b((size_t)N * F_IN * 2);
    float* bnsumsq = bnsum + 256;

    unsigned short* B1b = (unsigned short*)B1;
    unsigned short* B2b = (unsigned short*)B2;
    float*          B2f = (float*)B2;

    // CSR-build scratch aliased at head of B1 (dead before gather0 writes B1)
    int* cnt_src  = (int*)B1;
    int* cnt_dst  = cnt_src + N;
    int* fill     = cnt_dst + N;
    int* local    = fill + N;
    int* partials = local + N;

    // ---- CSR build + norms + weight prep + feat cast (pre-scaled by norm_src)
    hipMemsetAsync(cnt_src, 0, ((size_t)4 * N + 1024) * 4, stream);
    count_kernel<<<(E + 255) / 256, 256, 0, stream>>>(src, dst, cnt_src, cnt_dst, E);
    norm_kernel<<<(N + 255) / 256, 256, 0, stream>>>(cnt_src, cnt_dst, norm_src, norm_dst, N);
    scan_block_kernel<<<SCAN_B, 256, 0, stream>>>(cnt_dst, local, partials, N);
    scan_partials_kernel<<<1, 1024, 0, stream>>>(partials, SCAN_B);
    scan_add_kernel<<<(N + 255) / 256, 256, 0, stream>>>(local, partials, row_ptr, N);
    fill_kernel<<<(E + 255) / 256, 256, 0, stream>>>(src, dst, row_ptr, fill, csr_src, E);
    wt_kernel<128, 256, 256><<<(256 * 128 + 255) / 256, 256, 0, stream>>>(W0, Wt0);
    wt_kernel<256, 256, 256><<<(256 * 256 + 255) / 256, 256, 0, stream>>>(W1, Wt1);
    wt_kernel<256, 40, 64><<<(64 * 256 + 255) / 256, 256, 0, stream>>>(W2, Wt2);
    cast_feat_kernel<<<((unsigned)N * (F_IN / 4) + 255) / 256, 256, 0, stream>>>(feat, norm_src, featb);

    const int GB = (N + 127) / 128;

    // ---- layer 0: gather0 (pure sum) -> B1, GEMM0 (xnorm_dst, stats) -> B2
    {
        unsigned total = (unsigned)N * (F_IN / 4);
        gather_sum_kernel<F_IN><<<(total + 255) / 256, 256, 0, stream>>>(featb, row_ptr, csr_src, B1b, N);
    }
    hipMemsetAsync(bnsum, 0, 512 * 4, stream);
    mfma_gemm<128, 128, 4, 4, 2, true, true, 256, true, false><<<dim3(2, GB), 256, 0, stream>>>(
        B1b, Wt0, norm_dst, B2, nullptr, nullptr, bnsum, bnsumsq, N);
    bn_finalize_kernel<<<1, 256, 0, stream>>>(bnsum, bnsumsq, g0, beta0, bn_a0, bn_b0);

    // ---- layer 1: apply0 (BN+ReLU+norm_src) B2 -> B1, gather1 (pure sum) B1 -> B2,
    //               GEMM1 (xnorm_dst, stats) B2 -> B1
    apply_bn_scale_kernel<<<((unsigned)N * (F_HID / 8) + 255) / 256, 256, 0, stream>>>(
        B2b, bn_a0, bn_b0, norm_src, B1b);
    {
        unsigned total = (unsigned)N * (F_HID / 4);
        gather_sum_kernel<F_HID><<<(total + 255) / 256, 256, 0, stream>>>(B1b, row_ptr, csr_src, B2b, N);
    }
    hipMemsetAsync(bnsum, 0, 512 * 4, stream);
    mfma_gemm<256, 128, 4, 4, 2, true, true, 256, true, false><<<dim3(2, GB), 256, 0, stream>>>(
        B2b, Wt1, norm_dst, B1, nullptr, nullptr, bnsum, bnsumsq, N);
    bn_finalize_kernel<<<1, 256, 0, stream>>>(bnsum, bnsumsq, g1, beta1, bn_a1, bn_b1);

    // ---- layer 2: GEMM2 (BN+ReLU in staging, epilogue x norm_src) B1 -> B2f (N x 40 f32),
    //               final gather (pure sum, x norm_dst + b2) -> out
    mfma_gemm<256, 64, 2, 4, 1, true, false, 40, false, true><<<dim3(1, GB), 256, 0, stream>>>(
        B1b, Wt2, norm_src, B2, bn_a1, bn_b1, nullptr, nullptr, N);
    {
        unsigned total = (unsigned)N * (F_OUT / 4);
        gather_final_kernel<<<(total + 255) / 256, 256, 0, stream>>>(
            B2f, row_ptr, csr_src, norm_dst, b2, out, N);
    }
}